// Round 6
// baseline (467.944 us; speedup 1.0000x reference)
//
#include <hip/hip_runtime.h>

// CompetitiveLayer: K = param^2 (4096x4096 f32), 21 iterations of
//   AF = AT/(1+K@BF); BF = BT/(1+AF@K), then C = K*AF[:,None]*BF[None,:].
//
// Ladder: 1645 (R0 global RMW barrier + fences) -> 325 (R6: fence-free
// relaxed sync; L2-maintenance ops were 30us/phase) -> 309 (R7: group-local
// flags; fan-out was NOT the residual).
//
// R8: data-path restructure (sync model unchanged, R6-validated):
//   - NO atomics: each block stores its 256 partials as ONE coalesced slice
//     yrow_part[s][bC][R0..+255] / ycol_part[s][bR][C0..+255]; consumers sum
//     the 16 slices at stage time (16 latency-overlapped loads/thread).
//     Removes the 16-deep same-address RMW serialization + RMW-ack drain.
//   - NO zeroing phase: partials overwritten; mod-2 slot rotation, WAR-safe
//     by flag transitivity (slot-s writer at it+2 follows all it-readers).
//   - Per-wave flags: store -> wave vmcnt(0) drain -> flag; consumer polls
//     16 blocks x 4 waves = 64 flags with 64 lanes. One less block barrier.
//   - kl padded [16][9][260]: old 256-stride put ALL 64 lanes of every
//     ds_read_b128 on 8/32 banks (rl-stride 9216B = 0 mod 128B) -> the
//     2.15e7 SQ_LDS_BANK_CONFLICT. Pad makes bank starts (4rl+16cl)%32 =
//     even over all 8 groups -> conflict-free.

constexpr int N     = 4096;
constexpr int NITER = 21;
constexpr int NBLK  = 256;
constexpr int RREG  = 7;           // subtile rows 0..RREG-1 in VGPRs
constexpr int RLDS  = 16 - RREG;   // subtile rows RREG..15 in LDS
constexpr int KPAD  = 260;         // padded inner dim (bank decorrelation)

__device__ __forceinline__ float ld_agent(const float* p) {
    return __hip_atomic_load(p, __ATOMIC_RELAXED, __HIP_MEMORY_SCOPE_AGENT);
}
__device__ __forceinline__ void st_agent(float* p, float v) {
    __hip_atomic_store(p, v, __ATOMIC_RELAXED, __HIP_MEMORY_SCOPE_AGENT);
}
__device__ __forceinline__ unsigned ld_flag(const unsigned* p) {
    return __hip_atomic_load(p, __ATOMIC_RELAXED, __HIP_MEMORY_SCOPE_AGENT);
}
__device__ __forceinline__ void st_flag(unsigned* p, unsigned v) {
    __hip_atomic_store(p, v, __ATOMIC_RELAXED, __HIP_MEMORY_SCOPE_AGENT);
}
// Drain this wave's outstanding vmem (acked at coherence point). No cache ops.
__device__ __forceinline__ void drain_vmem() {
    asm volatile("s_waitcnt vmcnt(0)" ::: "memory");
}

// Block (bR,bC) owns the 256x256 tile of K. Lane (rl,cl) owns a 16x16 sub-tile.
__global__ void
__attribute__((amdgpu_flat_work_group_size(256, 256)))
__attribute__((amdgpu_waves_per_eu(1, 1)))
competitive_persistent(const float* __restrict__ AT, const float* __restrict__ BT,
                       const float* __restrict__ P,  float* __restrict__ C,
                       float* __restrict__ ws)
{
    const int b  = blockIdx.x;       // 0..255
    const int t  = threadIdx.x;      // 0..255
    const int bR = b >> 4, bC = b & 15;
    const int R0 = bR << 8, C0 = bC << 8;
    const int rl = t >> 4, cl = t & 15;
    const int row0 = R0 + rl * 16;
    const int col0 = C0 + cl * 16;
    const int w    = t >> 6;         // wave id 0..3

    // ws layout:
    //   frow flags: uint[4096]  slot (bR*64 + bC*4 + w), 16B stride   [zeroed]
    //   fcol flags: uint[4096]  slot (bC*64 + bR*4 + w), 16B stride   [zeroed]
    //   yrow_part[2][16][4096] floats at +8192   (slice bC, rows R0..R0+255)
    //   ycol_part[2][16][4096] floats at +8192+131072 (slice bR, cols C0..)
    unsigned* frow = (unsigned*)ws;
    unsigned* fcol = frow + 4096;
    float*    yrp  = ws + 8192;
    float*    ycp  = yrp + 2 * 16 * (size_t)N;

    __shared__ __align__(16) float xsh[256];
    __shared__ __align__(16) float red[1024];
    __shared__ __align__(16) float kl[16][RLDS][KPAD];   // ~146 KiB padded

    // ---- Load K = param^2: 7 rows/lane in registers, 9 rows/lane in LDS ----
    float k[RREG * 16];
    #pragma unroll
    for (int r = 0; r < 16; ++r) {
        const float4* src = (const float4*)(P + (size_t)(row0 + r) * N + col0);
        #pragma unroll
        for (int q = 0; q < 4; ++q) {
            float4 v = src[q];
            float4 s;
            s.x = v.x * v.x; s.y = v.y * v.y; s.z = v.z * v.z; s.w = v.w * v.w;
            if (r < RREG) {
                k[r * 16 + q * 4 + 0] = s.x;
                k[r * 16 + q * 4 + 1] = s.y;
                k[r * 16 + q * 4 + 2] = s.z;
                k[r * 16 + q * 4 + 3] = s.w;
            } else {
                *(float4*)&kl[rl][r - RREG][cl * 16 + q * 4] = s;
            }
        }
    }

    #pragma unroll 1
    for (int it = 0; it < NITER; ++it) {
        const unsigned lvl = (unsigned)(it + 1);
        const int s  = it & 1;          // partial slot this iteration writes
        const int sp = (it + 1) & 1;    // == (it-1)&1, slot of previous iter

        // ---- BF stage: BF = BT/(1+sum_r ycol_part[sp][r][C0+t]) ----
        if (it > 0) {
            if (t < 64) {   // 16 blocks x 4 waves of col-group bC at level it
                const unsigned* f = fcol + ((size_t)bC * 64 + t) * 4;
                while (ld_flag(f) < (unsigned)it) __builtin_amdgcn_s_sleep(1);
            }
            __syncthreads();
            float sum = 0.0f;
            const float* pp = ycp + (size_t)sp * 16 * N + C0 + t;
            #pragma unroll
            for (int r = 0; r < 16; ++r) sum += ld_agent(pp + (size_t)r * N);
            xsh[t] = BT[C0 + t] / (1.0f + sum);
        } else {
            xsh[t] = BT[C0 + t];        // y_col == 0 at it=0
        }
        __syncthreads();

        // ---- rowPhase: part_row[i] = sum_j K[i,j]*BF[j] (this tile) ----
        {
            float xv[16];
            const float4* xs4 = (const float4*)(xsh + cl * 16);
            #pragma unroll
            for (int q = 0; q < 4; ++q) {
                float4 v = xs4[q];
                xv[q * 4 + 0] = v.x; xv[q * 4 + 1] = v.y;
                xv[q * 4 + 2] = v.z; xv[q * 4 + 3] = v.w;
            }
            float part[16];
            #pragma unroll
            for (int r = 0; r < 16; ++r) part[r] = 0.0f;
            #pragma unroll
            for (int c = 0; c < 16; ++c) {
                const float x = xv[c];
                #pragma unroll
                for (int r = 0; r < RREG; ++r)
                    part[r] = fmaf(k[r * 16 + c], x, part[r]);
            }
            #pragma unroll
            for (int r = RREG; r < 16; ++r) {
                const float4* kp = (const float4*)&kl[rl][r - RREG][cl * 16];
                #pragma unroll
                for (int q = 0; q < 4; ++q) {
                    float4 kv = kp[q];
                    part[r] = fmaf(kv.x, xv[q * 4 + 0], part[r]);
                    part[r] = fmaf(kv.y, xv[q * 4 + 1], part[r]);
                    part[r] = fmaf(kv.z, xv[q * 4 + 2], part[r]);
                    part[r] = fmaf(kv.w, xv[q * 4 + 3], part[r]);
                }
            }
            #pragma unroll
            for (int off = 1; off < 16; off <<= 1) {
                #pragma unroll
                for (int r = 0; r < 16; ++r)
                    part[r] += __shfl_xor(part[r], off, 64);
            }
            if (cl == 0) {               // lane group rl holds rows rl*16..+15
                #pragma unroll
                for (int r = 0; r < 16; ++r)
                    red[rl * 16 + r] = part[r];
            }
        }
        __syncthreads();
        // Coalesced slice store + per-wave flag (store -> drain -> flag).
        st_agent(yrp + (size_t)s * 16 * N + (size_t)bC * N + R0 + t, red[t]);
        drain_vmem();
        if ((t & 63) == 0)
            st_flag(frow + ((size_t)bR * 64 + (size_t)bC * 4 + w) * 4, lvl);

        // ---- AF stage: AF = AT/(1+sum_c yrow_part[s][c][R0+t]) ----
        if (t < 64) {       // 16 blocks x 4 waves of row-group bR at level lvl
            const unsigned* f = frow + ((size_t)bR * 64 + t) * 4;
            while (ld_flag(f) < lvl) __builtin_amdgcn_s_sleep(1);
        }
        __syncthreads();
        {
            float sum = 0.0f;
            const float* pp = yrp + (size_t)s * 16 * N + R0 + t;
            #pragma unroll
            for (int c = 0; c < 16; ++c) sum += ld_agent(pp + (size_t)c * N);
            xsh[t] = AT[R0 + t] / (1.0f + sum);
        }
        __syncthreads();

        // ---- colPhase: part_col[j] = sum_i AF[i]*K[i,j] (this tile) ----
        {
            float av[16];
            #pragma unroll
            for (int r = 0; r < 16; ++r) av[r] = xsh[rl * 16 + r];
            float part[16];
            #pragma unroll
            for (int c = 0; c < 16; ++c) part[c] = 0.0f;
            #pragma unroll
            for (int r = 0; r < RREG; ++r) {
                const float a = av[r];
                #pragma unroll
                for (int c = 0; c < 16; ++c)
                    part[c] = fmaf(k[r * 16 + c], a, part[c]);
            }
            #pragma unroll
            for (int r = RREG; r < 16; ++r) {
                const float a = av[r];
                const float4* kp = (const float4*)&kl[rl][r - RREG][cl * 16];
                #pragma unroll
                for (int q = 0; q < 4; ++q) {
                    float4 kv = kp[q];
                    part[q * 4 + 0] = fmaf(kv.x, a, part[q * 4 + 0]);
                    part[q * 4 + 1] = fmaf(kv.y, a, part[q * 4 + 1]);
                    part[q * 4 + 2] = fmaf(kv.z, a, part[q * 4 + 2]);
                    part[q * 4 + 3] = fmaf(kv.w, a, part[q * 4 + 3]);
                }
            }
            #pragma unroll
            for (int c = 0; c < 16; ++c) {
                part[c] += __shfl_xor(part[c], 16, 64);
                part[c] += __shfl_xor(part[c], 32, 64);
            }
            if ((t & 63) < 16) {          // one lane per cl per wave
                #pragma unroll
                for (int c = 0; c < 16; ++c)
                    red[w * 256 + cl * 16 + c] = part[c];
            }
        }
        __syncthreads();
        {
            const float s4 = red[t] + red[256 + t] + red[512 + t] + red[768 + t];
            st_agent(ycp + (size_t)s * 16 * N + (size_t)bR * N + C0 + t, s4);
        }
        drain_vmem();
        if ((t & 63) == 0)
            st_flag(fcol + ((size_t)bC * 64 + (size_t)bR * 4 + w) * 4, lvl);
    }

    // ---- Final wait: col-group bC at level NITER (it=20 partials, slot 0) ----
    if (t < 64) {
        const unsigned* f = fcol + ((size_t)bC * 64 + t) * 4;
        while (ld_flag(f) < (unsigned)NITER) __builtin_amdgcn_s_sleep(1);
    }
    __syncthreads();

    // ---- Epilogue: C = K * AF[:,None] * BF[None,:]  (slot (NITER-1)&1 = 0) ----
    {
        float sa = 0.0f, sb = 0.0f;
        const float* pa = yrp + R0 + t;          // slot 0
        const float* pb = ycp + C0 + t;          // slot 0
        #pragma unroll
        for (int g = 0; g < 16; ++g) {
            sa += ld_agent(pa + (size_t)g * N);
            sb += ld_agent(pb + (size_t)g * N);
        }
        xsh[t] = AT[R0 + t] / (1.0f + sa);
        red[t] = BT[C0 + t] / (1.0f + sb);
    }
    __syncthreads();

    float af[16], bf[16];
    #pragma unroll
    for (int r = 0; r < 16; ++r) af[r] = xsh[rl * 16 + r];
    #pragma unroll
    for (int c = 0; c < 16; ++c) bf[c] = red[cl * 16 + c];

    #pragma unroll
    for (int r = 0; r < 16; ++r) {
        float4* dst = (float4*)(C + (size_t)(row0 + r) * N + col0);
        const float a = af[r];
        #pragma unroll
        for (int q = 0; q < 4; ++q) {
            float4 kv;
            if (r < RREG) {
                kv.x = k[r * 16 + q * 4 + 0];
                kv.y = k[r * 16 + q * 4 + 1];
                kv.z = k[r * 16 + q * 4 + 2];
                kv.w = k[r * 16 + q * 4 + 3];
            } else {
                kv = *(const float4*)&kl[rl][r - RREG][cl * 16 + q * 4];
            }
            float4 o;
            o.x = kv.x * a * bf[q * 4 + 0];
            o.y = kv.y * a * bf[q * 4 + 1];
            o.z = kv.z * a * bf[q * 4 + 2];
            o.w = kv.w * a * bf[q * 4 + 3];
            dst[q] = o;
        }
    }
}

extern "C" void kernel_launch(void* const* d_in, const int* in_sizes, int n_in,
                              void* d_out, int out_size, void* d_ws, size_t ws_size,
                              hipStream_t stream) {
    const float* AT = (const float*)d_in[0];
    const float* BT = (const float*)d_in[1];
    const float* P  = (const float*)d_in[2];
    float*       C  = (float*)d_out;
    float*       ws = (float*)d_ws;

    // Zero only the flag region (2 x 4096 uints = 32 KiB). Partial-sum
    // slices need no init: it=0 skips reads; every slice is fully written
    // before its flags release readers. (d_ws re-poisoned each timed call.)
    hipMemsetAsync(d_ws, 0, 8192 * sizeof(unsigned), stream);

    competitive_persistent<<<dim3(NBLK), dim3(256), 0, stream>>>(AT, BT, P, C, ws);
}

// Round 7
// 303.742 us; speedup vs baseline: 1.5406x; 1.5406x over previous
//
#include <hip/hip_runtime.h>

// CompetitiveLayer: K = param^2 (4096x4096 f32), 21 iterations of
//   AF = AT/(1+K@BF); BF = BT/(1+AF@K), then C = K*AF[:,None]*BF[None,:].
//
// Ladder: 1645 (R0) -> 325 (R6 fence-free relaxed sync) -> 309 (R7 group
// flags) -> 380 (R8 slice-store + per-wave flags + pad: REGRESSED; pad did
// not move bank-conflict counter -> conflicts are bpermute-dominated, not
// kl; per-wave flags added jitter; __syncthreads vmcnt(0) stalls on store
// acks).
//
// R9: SELF-VALIDATING DATA exchange -- no flags, no drains, no zeroing.
//   - Every exchanged partial is strictly > 0. Producer at iteration it
//     stores sgn(it)*part, sgn = +1 even / -1 odd. Consumers poll the data
//     words themselves until sign matches (|v| > 1e-9 rejects 0xAA poison
//     = -3.03e-13 and zeros, both parities). Decode = fabs: lossless.
//   - Slot period 3 (odd): stale slot content is same-producer same-address
//     -> coherence-ordered -> always opposite sign. WAR safety of reuse at
//     it+3 follows transitively through the poll chain (writer at it+3
//     happens-after all readers at it via reads-from + program order).
//   - ONE one-way L3 hop per handoff; producers never wait.
//   - Barriers are LDS-only (s_waitcnt lgkmcnt(0) + s_barrier): no vmcnt
//     store-ack stalls (all intra-block traffic is LDS).
//   - rowPhase: full butterfly leaves every lane all 16 row totals; each
//     lane stores exactly one element -> single coalesced st_agent/thread
//     (16-cndmask select avoids runtime reg indexing / scratch, rule #20).
//   - kl back to [16][9][256] (R7-proven; pad was VGPR cost, no win).

constexpr int N     = 4096;
constexpr int NITER = 21;
constexpr int NBLK  = 256;
constexpr int RREG  = 7;           // subtile rows 0..RREG-1 in VGPRs
constexpr int RLDS  = 16 - RREG;   // subtile rows RREG..15 in LDS

__device__ __forceinline__ float ld_agent(const float* p) {
    return __hip_atomic_load(p, __ATOMIC_RELAXED, __HIP_MEMORY_SCOPE_AGENT);
}
__device__ __forceinline__ void st_agent(float* p, float v) {
    __hip_atomic_store(p, v, __ATOMIC_RELAXED, __HIP_MEMORY_SCOPE_AGENT);
}
// LDS-only block barrier: no vmcnt drain (no store-ack stall).
__device__ __forceinline__ void sync_lds() {
    asm volatile("s_waitcnt lgkmcnt(0)" ::: "memory");
    __builtin_amdgcn_s_barrier();
    asm volatile("" ::: "memory");
}

// Poll 16 slice values at stride N, sign-validated; return decoded sum.
__device__ __forceinline__ float poll_sum16(const float* p, float sgn) {
    float v[16];
    #pragma unroll
    for (int g = 0; g < 16; ++g) v[g] = ld_agent(p + (size_t)g * N);
    for (;;) {
        bool ok = true;
        #pragma unroll
        for (int g = 0; g < 16; ++g) {
            if (!(v[g] * sgn > 1e-9f)) { ok = false; v[g] = ld_agent(p + (size_t)g * N); }
        }
        if (ok) break;
    }
    float s = 0.0f;
    #pragma unroll
    for (int g = 0; g < 16; ++g) s += v[g];
    return s * sgn;   // == sum of |v[g]|
}

// Block (bR,bC) owns the 256x256 tile of K. Lane (rl,cl) owns a 16x16 sub-tile.
__global__ void
__attribute__((amdgpu_flat_work_group_size(256, 256)))
__attribute__((amdgpu_waves_per_eu(1, 1)))
competitive_persistent(const float* __restrict__ AT, const float* __restrict__ BT,
                       const float* __restrict__ P,  float* __restrict__ C,
                       float* __restrict__ ws)
{
    const int b  = blockIdx.x;       // 0..255
    const int t  = threadIdx.x;      // 0..255
    const int bR = b >> 4, bC = b & 15;
    const int R0 = bR << 8, C0 = bC << 8;
    const int rl = t >> 4, cl = t & 15;
    const int row0 = R0 + rl * 16;
    const int col0 = C0 + cl * 16;
    const int w    = t >> 6;         // wave id 0..3

    // ws layout (host-zeroed slices; zero is invalid for both parities):
    //   yrp[3][16][4096]  row-phase partials (slot, slice bC, rows)
    //   ycp[3][16][4096]  col-phase partials (slot, slice bR, cols)
    float* yrp = ws;
    float* ycp = ws + 3 * 16 * (size_t)N;

    __shared__ __align__(16) float xsh[256];    // BF slice
    __shared__ __align__(16) float xsh2[256];   // AF slice
    __shared__ __align__(16) float red[1024];
    __shared__ __align__(16) float kl[16][RLDS][256];  // 144 KiB

    // ---- Load K = param^2: 7 rows/lane in registers, 9 rows/lane in LDS ----
    float k[RREG * 16];
    #pragma unroll
    for (int r = 0; r < 16; ++r) {
        const float4* src = (const float4*)(P + (size_t)(row0 + r) * N + col0);
        #pragma unroll
        for (int q = 0; q < 4; ++q) {
            float4 v = src[q];
            float4 s;
            s.x = v.x * v.x; s.y = v.y * v.y; s.z = v.z * v.z; s.w = v.w * v.w;
            if (r < RREG) {
                k[r * 16 + q * 4 + 0] = s.x;
                k[r * 16 + q * 4 + 1] = s.y;
                k[r * 16 + q * 4 + 2] = s.z;
                k[r * 16 + q * 4 + 3] = s.w;
            } else {
                *(float4*)&kl[rl][r - RREG][cl * 16 + q * 4] = s;
            }
        }
    }
    sync_lds();

    #pragma unroll 1
    for (int it = 0; it < NITER; ++it) {
        const int   sC      = it % 3;
        const float sgn_cur = (it & 1) ? -1.0f : 1.0f;

        // ---- BF stage: BF = BT/(1+sum_r ycp[sP][r][C0+t]) ----
        if (it > 0) {
            const int sP = (it + 2) % 3;            // slot of iteration it-1
            const float sum = poll_sum16(ycp + (size_t)sP * 16 * N + C0 + t, -sgn_cur);
            xsh[t] = BT[C0 + t] / (1.0f + sum);
        } else {
            xsh[t] = BT[C0 + t];                    // y_col == 0 at it=0
        }
        sync_lds();

        // ---- rowPhase: y_row partial for this tile ----
        {
            float xv[16];
            const float4* xs4 = (const float4*)(xsh + cl * 16);
            #pragma unroll
            for (int q = 0; q < 4; ++q) {
                float4 v = xs4[q];
                xv[q * 4 + 0] = v.x; xv[q * 4 + 1] = v.y;
                xv[q * 4 + 2] = v.z; xv[q * 4 + 3] = v.w;
            }
            float part[16];
            #pragma unroll
            for (int r = 0; r < 16; ++r) part[r] = 0.0f;
            #pragma unroll
            for (int c = 0; c < 16; ++c) {
                const float x = xv[c];
                #pragma unroll
                for (int r = 0; r < RREG; ++r)
                    part[r] = fmaf(k[r * 16 + c], x, part[r]);
            }
            #pragma unroll
            for (int r = RREG; r < 16; ++r) {
                const float4* kp = (const float4*)&kl[rl][r - RREG][cl * 16];
                #pragma unroll
                for (int q = 0; q < 4; ++q) {
                    float4 kv = kp[q];
                    part[r] = fmaf(kv.x, xv[q * 4 + 0], part[r]);
                    part[r] = fmaf(kv.y, xv[q * 4 + 1], part[r]);
                    part[r] = fmaf(kv.z, xv[q * 4 + 2], part[r]);
                    part[r] = fmaf(kv.w, xv[q * 4 + 3], part[r]);
                }
            }
            // Full butterfly over cl-bits: every lane ends with all 16 totals.
            #pragma unroll
            for (int off = 1; off < 16; off <<= 1) {
                #pragma unroll
                for (int r = 0; r < 16; ++r)
                    part[r] += __shfl_xor(part[r], off, 64);
            }
            // Lane (rl,cl) stores row R0 + rl*16 + cl -> address base + R0 + t
            // (fully coalesced). Static 16-way select avoids runtime reg index.
            float myv = part[0];
            #pragma unroll
            for (int r = 1; r < 16; ++r) myv = (cl == r) ? part[r] : myv;
            st_agent(yrp + ((size_t)sC * 16 + bC) * N + R0 + t, sgn_cur * myv);
        }

        // ---- AF stage: AF = AT/(1+sum_c yrp[sC][c][R0+t]) ----
        {
            const float sum = poll_sum16(yrp + (size_t)sC * 16 * N + R0 + t, sgn_cur);
            xsh2[t] = AT[R0 + t] / (1.0f + sum);
        }
        sync_lds();

        // ---- colPhase: y_col partial for this tile ----
        {
            float av[16];
            #pragma unroll
            for (int r = 0; r < 16; ++r) av[r] = xsh2[rl * 16 + r];
            float part[16];
            #pragma unroll
            for (int c = 0; c < 16; ++c) part[c] = 0.0f;
            #pragma unroll
            for (int r = 0; r < RREG; ++r) {
                const float a = av[r];
                #pragma unroll
                for (int c = 0; c < 16; ++c)
                    part[c] = fmaf(k[r * 16 + c], a, part[c]);
            }
            #pragma unroll
            for (int r = RREG; r < 16; ++r) {
                const float a = av[r];
                const float4* kp = (const float4*)&kl[rl][r - RREG][cl * 16];
                #pragma unroll
                for (int q = 0; q < 4; ++q) {
                    float4 kv = kp[q];
                    part[q * 4 + 0] = fmaf(kv.x, a, part[q * 4 + 0]);
                    part[q * 4 + 1] = fmaf(kv.y, a, part[q * 4 + 1]);
                    part[q * 4 + 2] = fmaf(kv.z, a, part[q * 4 + 2]);
                    part[q * 4 + 3] = fmaf(kv.w, a, part[q * 4 + 3]);
                }
            }
            #pragma unroll
            for (int c = 0; c < 16; ++c) {
                part[c] += __shfl_xor(part[c], 16, 64);
                part[c] += __shfl_xor(part[c], 32, 64);
            }
            if ((t & 63) < 16) {          // one lane per cl per wave
                #pragma unroll
                for (int c = 0; c < 16; ++c)
                    red[w * 256 + cl * 16 + c] = part[c];
            }
            sync_lds();
            const float s4 = red[t] + red[256 + t] + red[512 + t] + red[768 + t];
            st_agent(ycp + ((size_t)sC * 16 + bR) * N + C0 + t, sgn_cur * s4);
        }
    }

    // ---- Epilogue: C = K * AF[:,None] * BF[None,:] ----
    // AF(20) is still in xsh2. BF_final from y_col(20): slot 20%3=2, sign +.
    sync_lds();   // all waves past their red reads before red is reused
    {
        const float sum = poll_sum16(ycp + (size_t)2 * 16 * N + C0 + t, 1.0f);
        red[t] = BT[C0 + t] / (1.0f + sum);
    }
    sync_lds();

    float af[16], bf[16];
    #pragma unroll
    for (int r = 0; r < 16; ++r) af[r] = xsh2[rl * 16 + r];
    #pragma unroll
    for (int c = 0; c < 16; ++c) bf[c] = red[cl * 16 + c];

    #pragma unroll
    for (int r = 0; r < 16; ++r) {
        float4* dst = (float4*)(C + (size_t)(row0 + r) * N + col0);
        const float a = af[r];
        #pragma unroll
        for (int q = 0; q < 4; ++q) {
            float4 kv;
            if (r < RREG) {
                kv.x = k[r * 16 + q * 4 + 0];
                kv.y = k[r * 16 + q * 4 + 1];
                kv.z = k[r * 16 + q * 4 + 2];
                kv.w = k[r * 16 + q * 4 + 3];
            } else {
                kv = *(const float4*)&kl[rl][r - RREG][cl * 16 + q * 4];
            }
            float4 o;
            o.x = kv.x * a * bf[q * 4 + 0];
            o.y = kv.y * a * bf[q * 4 + 1];
            o.z = kv.z * a * bf[q * 4 + 2];
            o.w = kv.w * a * bf[q * 4 + 3];
            dst[q] = o;
        }
    }
}

extern "C" void kernel_launch(void* const* d_in, const int* in_sizes, int n_in,
                              void* d_out, int out_size, void* d_ws, size_t ws_size,
                              hipStream_t stream) {
    const float* AT = (const float*)d_in[0];
    const float* BT = (const float*)d_in[1];
    const float* P  = (const float*)d_in[2];
    float*       C  = (float*)d_out;
    float*       ws = (float*)d_ws;

    // Zero the 2x3x16x4096 slice region (1.5 MiB). Zero (like the 0xAA
    // poison = -3.03e-13) is sign/magnitude-invalid for both parities, so
    // any pre-state is safe; memset is cheap insurance for unpoisoned calls.
    hipMemsetAsync(d_ws, 0, 2 * 3 * 16 * (size_t)N * sizeof(float), stream);

    competitive_persistent<<<dim3(NBLK), dim3(256), 0, stream>>>(AT, BT, P, C, ws);
}